// Round 3
// baseline (226.242 us; speedup 1.0000x reference)
//
#include <hip/hip_runtime.h>

#define NPG 100     // nodes per graph
#define HF 64       // hidden width
#define SAT 136     // Tc row stride (bf16): 128 + 8 pad
#define CMW 29      // count-matrix words per row (29 odd -> conflict-free column reads)
#define XBS 520     // xbuf plane stride in dwords (512 slots + 8 pad)

typedef float  f4   __attribute__((ext_vector_type(4)));
typedef float  f16v __attribute__((ext_vector_type(16)));
typedef short  bf8  __attribute__((ext_vector_type(8)));

#define SZ_TC   (HF * SAT * 2)          // 17408 (single Tc buffer)
#define OFF_XB  SZ_TC                   // xbuf: [8 words][XBS] dwords, transposed
#define SZ_XB   (8 * XBS * 4)           // 16640
#define OFF_MISC (OFF_XB + SZ_XB)       // 34048
#define SMEM_BYTES (OFF_MISC + 2048)    // 36096 -> 2 blocks/CU (VGPR-bound), 72KB LDS/CU
// misc: dis[112]@0 | b_all[192]@448 | gvn[64]@1216 | zf[32]@1472 | logits@1600 | lsep@1664

// bf16 weight workspace (d_ws), layout Wt[k5][fo][fi]:
//   W1t [5][64][16] @ 0 (fi zero-padded 3->16) | W2t [5][64][64] @ 5120 | W3t @ 25600
#define WT_TOTAL 46080

__device__ __forceinline__ unsigned short f2bf(float f) {
    unsigned u = __float_as_uint(f);
    u += 0x7fffu + ((u >> 16) & 1u);
    return (unsigned short)(u >> 16);
}
__device__ __forceinline__ unsigned cvt_pk_bf16(float lo, float hi) {
    unsigned r;
    asm("v_cvt_pk_bf16_f32 %0, %1, %2" : "=v"(r) : "v"(lo), "v"(hi));
    return r;
}
__device__ __forceinline__ f16v zerov16() {
    f16v z;
    #pragma unroll
    for (int i = 0; i < 16; i++) z[i] = 0.f;
    return z;
}

union BF8U { unsigned u[4]; bf8 b; };

__global__ void wconv(const float* __restrict__ W1, const float* __restrict__ W2,
                      const float* __restrict__ W3, unsigned short* __restrict__ ws)
{
    int idx = blockIdx.x * 256 + threadIdx.x;
    if (idx >= WT_TOTAL) return;
    float v;
    if (idx < 5120) {
        int k5 = idx >> 10, rem = idx & 1023, fo = rem >> 4, fi = rem & 15;
        v = (fi < 3) ? W1[(k5 * 3 + fi) * HF + fo] : 0.f;
    } else if (idx < 25600) {
        int j = idx - 5120;
        int k5 = j >> 12, rem = j & 4095, fo = rem >> 6, fi = rem & 63;
        v = W2[(k5 * HF + fi) * HF + fo];
    } else {
        int j = idx - 25600;
        int k5 = j >> 12, rem = j & 4095, fo = rem >> 6, fi = rem & 63;
        v = W3[(k5 * HF + fi) * HF + fo];
    }
    ws[idx] = f2bf(v);
}

// Transposed-dataflow ChebNet, fo-SPLIT: one block per graph, 512 threads = 8 waves.
// Wave wg: np-tile = wg>>1 (cols nb..nb+31), ct = wg&1 (fo rows 32ct..32ct+31).
// Per-wave registers: afT[7] (Ahat^T B-frags, 28) + prev[8]/oldr[8] (T_{s-1}/T_{s-2},
// own fo half, 16) + acc (16) ~= 60 persistent, ~115 peak -> no spill at 128 VGPR
// (round-2 lesson: 190-VGPR peak at 128 budget = 22MB scratch traffic on the
// critical path).
// TW needs BOTH fi halves: own half from prev regs, partner half via xbuf
// (transposed [8][520] dword planes, conflict-free b32), then the SAME
// permlane32_swap B-frag construction as round 2 (verified numerics).
// Single Tc + single xbuf -> 2 barriers/stage; 2 independent blocks/CU hide them.
__launch_bounds__(512, 2)
__global__ void chebreg(const float* __restrict__ x, const int* __restrict__ ei,
                        const float* __restrict__ lambda_max,
                        const unsigned short* __restrict__ Wt,
                        const float* __restrict__ b1, const float* __restrict__ b2,
                        const float* __restrict__ b3,
                        const float* __restrict__ bng, const float* __restrict__ bnb,
                        const float* __restrict__ bnm, const float* __restrict__ bnv,
                        const float* __restrict__ fc1w, const float* __restrict__ fc1b,
                        const float* __restrict__ fc2w, const float* __restrict__ fc2b,
                        float* __restrict__ out, int E_total, int epg)
{
    extern __shared__ char sm[];
    const int tid = threadIdx.x;
    const int g = blockIdx.x;
    const int ebase = g * epg, nbase = g * NPG;
    const int wg = tid >> 6, lane = tid & 63;
    const int l31 = lane & 31, hh = lane >> 5;
    const int tile = wg >> 1, ct = wg & 1;
    const int nb = 32 * tile;
    const int np = nb + l31;
    const bool npv = (np < NPG);
    const int foB = 32 * ct;

    unsigned* Cm  = (unsigned*)sm;                     // overlays Tc (14848 <= 17408)
    unsigned* xb  = (unsigned*)(sm + OFF_XB);
    float* dis    = (float*)(sm + OFF_MISC);
    float* b_all  = (float*)(sm + OFF_MISC + 448);
    float* gvn    = (float*)(sm + OFF_MISC + 1216);
    float* zf     = (float*)(sm + OFF_MISC + 1472);
    float* logits = (float*)(sm + OFF_MISC + 1600);
    float* lsep   = (float*)(sm + OFF_MISC + 1664);

    const int xslot_me = wg * 64 + lane;
    const int xslot_pa = (wg ^ 1) * 64 + lane;

    const float lam = lambda_max[g];
    const float two_l = 2.0f / lam;
    const float cl = two_l - 1.0f;

    // ---------------- u8 count matrix + dis + biases ----------------
    for (int i = tid; i < (128 * CMW) / 4; i += 512)
        ((f4*)Cm)[i] = (f4){0.f, 0.f, 0.f, 0.f};
    __syncthreads();
    for (int e = tid; e < epg; e += 512) {
        int r = ei[ebase + e] - nbase;
        int c = ei[E_total + ebase + e] - nbase;
        atomicAdd(&Cm[r * CMW + (c >> 2)], 1u << (8 * (c & 3)));
    }
    __syncthreads();
    if (tid < 112) {
        float dv = 0.f;
        if (tid < NPG) {
            unsigned s = 0;
            #pragma unroll
            for (int w = 0; w < 25; w++) {
                unsigned u = Cm[tid * CMW + w];
                s += (u & 255) + ((u >> 8) & 255) + ((u >> 16) & 255) + (u >> 24);
            }
            dv = s > 0 ? rsqrtf((float)s) : 0.f;
        }
        dis[tid] = dv;
    }
    if (tid < 192)
        b_all[tid] = (tid < 64) ? b1[tid] : (tid < 128) ? b2[tid - 64] : b3[tid - 128];
    __syncthreads();

    // ---------------- Ahat^T B-fragments -> registers (once) ----------------
    bf8 afT[7];
    {
        float base = npv ? (-two_l * dis[np]) : 0.f;
        #pragma unroll
        for (int Ks = 0; Ks < 7; Ks++) {
            int n0 = Ks * 16 + 8 * hh;
            unsigned w0 = npv ? Cm[np * CMW + (n0 >> 2)]     : 0u;
            unsigned w1 = npv ? Cm[np * CMW + (n0 >> 2) + 1] : 0u;
            float vv[8];
            #pragma unroll
            for (int j = 0; j < 8; j++) {
                int n = n0 + j;
                unsigned cnt = (((j < 4) ? w0 : w1) >> (8 * (n & 3))) & 255u;
                float v = base * (float)cnt * dis[n];
                if (npv && n == np) v += cl;
                vv[j] = v;
            }
            BF8U t;
            #pragma unroll
            for (int p = 0; p < 4; p++) t.u[p] = cvt_pk_bf16(vv[2 * p], vv[2 * p + 1]);
            afT[Ks] = t.b;
        }
    }
    __syncthreads();   // Cm reads done before Tc overlay is zeroed

    // ---------------- zero Tc + xbuf, init T0 = x^T ----------------
    for (int i = tid; i < OFF_MISC / 16; i += 512)
        ((f4*)sm)[i] = (f4){0.f, 0.f, 0.f, 0.f};
    __syncthreads();

    unsigned prev[8], oldr[8];
    #pragma unroll
    for (int p = 0; p < 8; p++) prev[p] = 0u;

    if (ct == 0 && hh == 0 && npv) {
        float x0 = x[(nbase + np) * 3 + 0];
        float x1 = x[(nbase + np) * 3 + 1];
        float x2 = x[(nbase + np) * 3 + 2];
        prev[0] = cvt_pk_bf16(x0, x1);
        prev[1] = cvt_pk_bf16(x2, 0.f);
        *(unsigned short*)(sm + (0 * SAT + np) * 2) = (unsigned short)(prev[0] & 0xffff);
        *(unsigned short*)(sm + (1 * SAT + np) * 2) = (unsigned short)(prev[0] >> 16);
        *(unsigned short*)(sm + (2 * SAT + np) * 2) = (unsigned short)(prev[1] & 0xffff);
    }
    if (ct == 0) {
        xb[0 * XBS + xslot_me] = prev[0];
        xb[1 * XBS + xslot_me] = prev[1];
    }
    __syncthreads();

    // ---------------- 3 ChebConv layers ----------------
    f16v acc;

    for (int L = 0; L < 3; L++) {
        const bool l0 = (L == 0);
        const unsigned short* Wl = l0 ? Wt : (Wt + (L == 1 ? 5120 : 25600));
        const int wstr = l0 ? 16 : 64;
        const int nKs  = l0 ? 1 : 4;
        const bool doLH = !(l0 && ct == 1);   // L0: fo rows 32..63 of T stay zero
        acc = zerov16();

        // TW B-frag from registers via permlane32_swap; fiLo = fi 0..31, fiHi = 32..63.
        auto TWK = [&](const unsigned (&fiLo)[8], const unsigned (&fiHi)[8], const int k5) {
            #pragma unroll
            for (int Ks = 0; Ks < 4; Ks++) {
                if (Ks < nKs) {
                    unsigned a0, b0, a1, b1v;
                    if (Ks < 2) {
                        a0 = fiLo[4 * (Ks & 1) + 0]; b0  = fiLo[4 * (Ks & 1) + 2];
                        a1 = fiLo[4 * (Ks & 1) + 1]; b1v = fiLo[4 * (Ks & 1) + 3];
                    } else {
                        a0 = fiHi[4 * (Ks & 1) + 0]; b0  = fiHi[4 * (Ks & 1) + 2];
                        a1 = fiHi[4 * (Ks & 1) + 1]; b1v = fiHi[4 * (Ks & 1) + 3];
                    }
                    asm volatile("v_permlane32_swap_b32 %0, %1" : "+v"(a0), "+v"(b0));
                    asm volatile("v_permlane32_swap_b32 %0, %1" : "+v"(a1), "+v"(b1v));
                    BF8U bfr; bfr.u[0] = a0; bfr.u[1] = a1; bfr.u[2] = b0; bfr.u[3] = b1v;
                    bf8 wf = *(const bf8*)(Wl + (k5 * 64 + foB + l31) * wstr + Ks * 16 + 8 * hh);
                    acc = __builtin_amdgcn_mfma_f32_32x32x16_bf16(wf, bfr.b, acc, 0, 0, 0);
                }
            }
        };

        for (int s = 1; s <= 4; s++) {
            // ---- phase A: reads + compute ----
            unsigned prevP[8];
            const int pl = l0 ? 4 : 8;
            #pragma unroll
            for (int p = 0; p < 8; p++)
                if (p < pl) prevP[p] = xb[p * XBS + xslot_pa];

            bf8 Af[7];
            if (doLH) {
                #pragma unroll
                for (int Ks = 0; Ks < 7; Ks++)
                    Af[Ks] = *(const bf8*)(sm + ((foB + l31) * SAT + Ks * 16 + 8 * hh) * 2);
            }

            if (ct == 0) TWK(prev, prevP, s - 1); else TWK(prevP, prev, s - 1);

            if (doLH) {
                f16v c = zerov16();
                #pragma unroll
                for (int Ks = 0; Ks < 7; Ks++)
                    c = __builtin_amdgcn_mfma_f32_32x32x16_bf16(Af[Ks], afT[Ks], c, 0, 0, 0);
                const int pmax = l0 ? 2 : 8;
                #pragma unroll
                for (int p = 0; p < 8; p++) {
                    if (p < pmax) {
                        float ve = c[2 * p], vo = c[2 * p + 1];
                        if (s >= 2) {
                            unsigned o = oldr[p];
                            ve = 2.f * ve - __uint_as_float(o << 16);
                            vo = 2.f * vo - __uint_as_float(o & 0xffff0000u);
                        }
                        oldr[p] = prev[p];
                        prev[p] = cvt_pk_bf16(ve, vo);
                    }
                }
            }
            __syncthreads();   // all Tc + xbuf reads of T_{s-1} complete

            // ---- phase B: publish T_s ----
            if (doLH) {
                if (s < 4) {
                    if (l0) {
                        if (hh == 0) {
                            *(unsigned short*)(sm + (0 * SAT + np) * 2) = (unsigned short)(prev[0] & 0xffff);
                            *(unsigned short*)(sm + (1 * SAT + np) * 2) = (unsigned short)(prev[0] >> 16);
                            *(unsigned short*)(sm + (2 * SAT + np) * 2) = (unsigned short)(prev[1] & 0xffff);
                        }
                    } else {
                        #pragma unroll
                        for (int p = 0; p < 8; p++) {
                            int fo = foB + ((2 * p) & 3) + 8 * (p >> 1) + 4 * hh;
                            char* ad = sm + (fo * SAT + np) * 2;
                            *(unsigned short*)ad = (unsigned short)(prev[p] & 0xffff);
                            *(unsigned short*)(ad + SAT * 2) = (unsigned short)(prev[p] >> 16);
                        }
                    }
                }
                if (l0) {
                    xb[0 * XBS + xslot_me] = prev[0];
                    xb[1 * XBS + xslot_me] = prev[1];
                } else {
                    #pragma unroll
                    for (int p = 0; p < 8; p++)
                        xb[p * XBS + xslot_me] = prev[p];
                }
            }
            __syncthreads();   // T_s visible
        }

        // TW k5=4 term: own prev + partner T_4 from xbuf
        {
            unsigned prevP[8];
            const int pl = l0 ? 4 : 8;
            #pragma unroll
            for (int p = 0; p < 8; p++)
                if (p < pl) prevP[p] = xb[p * XBS + xslot_pa];
            if (ct == 0) TWK(prev, prevP, 4); else TWK(prevP, prev, 4);
        }

        if (L < 2) {
            __syncthreads();   // TWreg(4) xbuf reads done before overwrites
            const float* bl = b_all + L * 64;
            #pragma unroll
            for (int p = 0; p < 8; p++) {
                int fo = foB + ((2 * p) & 3) + 8 * (p >> 1) + 4 * hh;
                float2 bb = *(const float2*)(bl + fo);   // fo even -> 8B aligned
                float ve = fmaxf(acc[2 * p]     + bb.x, 0.f);
                float vo = fmaxf(acc[2 * p + 1] + bb.y, 0.f);
                prev[p] = cvt_pk_bf16(ve, vo);
                char* ad = sm + (fo * SAT + np) * 2;
                *(unsigned short*)ad = (unsigned short)(prev[p] & 0xffff);
                *(unsigned short*)(ad + SAT * 2) = (unsigned short)(prev[p] >> 16);
                xb[p * XBS + xslot_me] = prev[p];
            }
            __syncthreads();
        } else {
            __syncthreads();   // all Tc/xbuf reads drained before Sc overlay
            float* Sc = (float*)sm;          // f32 [64][132] = 33792 <= 34048
            const float* bl = b_all + 128;
            #pragma unroll
            for (int p = 0; p < 8; p++) {
                int fo = foB + ((2 * p) & 3) + 8 * (p >> 1) + 4 * hh;
                float2 bb = *(const float2*)(bl + fo);
                float ve = fmaxf(acc[2 * p]     + bb.x, 0.f);
                float vo = fmaxf(acc[2 * p + 1] + bb.y, 0.f);
                if (npv) {
                    Sc[fo * 132 + np]       = ve;
                    Sc[(fo + 1) * 132 + np] = vo;
                }
            }
            __syncthreads();
            if (tid < HF) {
                float ssum = 0.f;
                #pragma unroll
                for (int k = 0; k < 25; k++) {
                    f4 v = *(const f4*)(Sc + tid * 132 + 4 * k);
                    ssum += v[0] + v[1] + v[2] + v[3];
                }
                float gv = ssum * (1.0f / NPG);
                gv = (gv - bnm[tid]) * rsqrtf(bnv[tid] + 1e-5f) * bng[tid] + bnb[tid];
                gvn[tid] = gv;
            }
            __syncthreads();
        }
    }

    // ---------------- MLP + log_softmax ----------------
    if (tid < 32) {
        float a = fc1b[tid];
        for (int f = 0; f < HF; f++) a += gvn[f] * fc1w[f * 32 + tid];
        zf[tid] = fmaxf(a, 0.f);
    }
    __syncthreads();
    if (tid < 10) {
        float a = fc2b[tid];
        for (int k = 0; k < 32; k++) a += zf[k] * fc2w[k * 10 + tid];
        logits[tid] = a;
    }
    __syncthreads();
    if (tid == 0) {
        float m = logits[0];
        for (int i = 1; i < 10; i++) m = fmaxf(m, logits[i]);
        float s = 0.f;
        for (int i = 0; i < 10; i++) s += expf(logits[i] - m);
        lsep[0] = m + logf(s);
    }
    __syncthreads();
    if (tid < 10) out[g * 10 + tid] = logits[tid] - lsep[0];
}

extern "C" void kernel_launch(void* const* d_in, const int* in_sizes, int n_in,
                              void* d_out, int out_size, void* d_ws, size_t ws_size,
                              hipStream_t stream) {
    const float* x    = (const float*)d_in[0];
    const int*   ei   = (const int*)d_in[1];
    const float* lmax = (const float*)d_in[3];
    const float* W1   = (const float*)d_in[4];
    const float* b1   = (const float*)d_in[5];
    const float* W2   = (const float*)d_in[6];
    const float* b2   = (const float*)d_in[7];
    const float* W3   = (const float*)d_in[8];
    const float* b3   = (const float*)d_in[9];
    const float* bng  = (const float*)d_in[10];
    const float* bnb  = (const float*)d_in[11];
    const float* bnm  = (const float*)d_in[12];
    const float* bnv  = (const float*)d_in[13];
    const float* fc1w = (const float*)d_in[14];
    const float* fc1b = (const float*)d_in[15];
    const float* fc2w = (const float*)d_in[16];
    const float* fc2b = (const float*)d_in[17];

    const int E = in_sizes[1] / 2;
    const int G = in_sizes[3];
    const int epg = E / G;

    unsigned short* Wt = (unsigned short*)d_ws;

    wconv<<<(WT_TOTAL + 255) / 256, 256, 0, stream>>>(W1, W2, W3, Wt);

    hipFuncSetAttribute((const void*)chebreg,
                        hipFuncAttributeMaxDynamicSharedMemorySize, SMEM_BYTES);

    chebreg<<<G, 512, SMEM_BYTES, stream>>>(x, ei, lmax, Wt, b1, b2, b3,
                                            bng, bnb, bnm, bnv, fc1w, fc1b, fc2w, fc2b,
                                            (float*)d_out, E, epg);
}

// Round 4
// 159.526 us; speedup vs baseline: 1.4182x; 1.4182x over previous
//
#include <hip/hip_runtime.h>

#define NPG 100     // nodes per graph
#define HF 64       // hidden width
#define ST 72       // Trm row stride (bf16): 64 + 8 pad (9 units of 16B, 9%8=1 -> conflict-free b128)
#define SAT 136     // Tc row stride (bf16): 128 + 8 pad (17 units, 17%8=1 -> conflict-free b128)
#define CMW 29      // count-matrix words per row (ODD -> conflict-free strided column reads; R0/R1's
                    // CMW=28 was the source of 2.57M bank-conflict cycles: gcd(28,32)=4 -> 8-way)

typedef float  f4   __attribute__((ext_vector_type(4)));
typedef float  f16v __attribute__((ext_vector_type(16)));
typedef short  bf8  __attribute__((ext_vector_type(8)));

#define SZ_TC  (HF * SAT * 2)            // 17408 per Tc buffer
#define SZ_TRM (128 * ST * 2)            // 18432 per Trm buffer
#define OFF_TRM (2 * SZ_TC)              // 34816: Tc0@0, Tc1@17408, Trm0@34816, Trm1@53248
#define OFF_MISC (OFF_TRM + 2 * SZ_TRM)  // 71680
#define SMEM_BYTES (OFF_MISC + 1280)     // 72960 -> 2 blocks/CU by LDS
// misc: dis[112]@0 (448) | pool[64]@448 | gvn[64]@704 | zf[32]@960 | logits@1088 | lsep@1152

// bf16 weight workspace (d_ws), layout Wt[k5][fo][fi]:
//   W1t [5][64][16] @ 0 (fi zero-padded 3->16) | W2t [5][64][64] @ 5120 | W3t @ 25600
#define WT_TOTAL 46080

__device__ __forceinline__ unsigned short f2bf(float f) {
    unsigned u = __float_as_uint(f);
    u += 0x7fffu + ((u >> 16) & 1u);   // round-to-nearest-even
    return (unsigned short)(u >> 16);
}
// HW packed f32->bf16 (RNE), lo -> bits[15:0], hi -> bits[31:16].
__device__ __forceinline__ unsigned cvt_pk_bf16(float lo, float hi) {
    unsigned r;
    asm("v_cvt_pk_bf16_f32 %0, %1, %2" : "=v"(r) : "v"(lo), "v"(hi));
    return r;
}
__device__ __forceinline__ f16v zerov16() {
    f16v z;
    #pragma unroll
    for (int i = 0; i < 16; i++) z[i] = 0.f;
    return z;
}
// LDS-only barrier: lgkmcnt(0) drain + s_barrier. Unlike __syncthreads (which
// drains vmcnt(0) too), this keeps global weight loads in flight across barriers.
// All intra-loop cross-wave communication is via LDS -> lgkm drain is sufficient.
__device__ __forceinline__ void bar_lgkm() {
    asm volatile("s_waitcnt lgkmcnt(0)" ::: "memory");
    __builtin_amdgcn_s_barrier();
    __builtin_amdgcn_sched_barrier(0);
}

union BF8U { unsigned u[4]; bf8 b; };

__global__ void wconv(const float* __restrict__ W1, const float* __restrict__ W2,
                      const float* __restrict__ W3, unsigned short* __restrict__ ws)
{
    int idx = blockIdx.x * 256 + threadIdx.x;
    if (idx >= WT_TOTAL) return;
    float v;
    if (idx < 5120) {
        int k5 = idx >> 10, rem = idx & 1023, fo = rem >> 4, fi = rem & 15;
        v = (fi < 3) ? W1[(k5 * 3 + fi) * HF + fo] : 0.f;
    } else if (idx < 25600) {
        int j = idx - 5120;
        int k5 = j >> 12, rem = j & 4095, fo = rem >> 6, fi = rem & 63;
        v = W2[(k5 * HF + fi) * HF + fo];
    } else {
        int j = idx - 25600;
        int k5 = j >> 12, rem = j & 4095, fo = rem >> 6, fi = rem & 63;
        v = W3[(k5 * HF + fi) * HF + fo];
    }
    ws[idx] = f2bf(v);
}

// R1 structure (best measured: 4 waves, wave=(np-tile-pair, fo-half), A-hat in regs,
// dual-orientation T) with synchronization halved:
//  - Tc AND Trm ping-pong on stage parity -> ONE barrier per Chebyshev stage
//    (R1 had two: WAR before writes + RAW after). T_s lives at parity (pb+s)&1,
//    pb = L&1. Stage s reads parity rp=(pb+s-1)&1, writes wp=rp^1; the only
//    hazard (stage-s writes vs stage-(s-1) reads of the same parity) is covered
//    by the single end-of-stage barrier.
//  - lgkm-only barriers (no vmcnt drain -> weight loads overlap barriers).
//  - CMW 29 (odd stride kills the 8-way Cm read conflicts; -2.57M conflict cycles).
//  - dead stage-4 Tc writes skipped; layer-end epilogue writes opposite parity
//    (= next layer's read parity) so no extra WAR barrier.
// Arithmetic/accumulation order identical to R1 -> absmax must match exactly.
__launch_bounds__(256, 2)
__global__ void chebreg(const float* __restrict__ x, const int* __restrict__ ei,
                        const float* __restrict__ lambda_max,
                        const unsigned short* __restrict__ Wt,
                        const float* __restrict__ b1, const float* __restrict__ b2,
                        const float* __restrict__ b3,
                        const float* __restrict__ bng, const float* __restrict__ bnb,
                        const float* __restrict__ bnm, const float* __restrict__ bnv,
                        const float* __restrict__ fc1w, const float* __restrict__ fc1b,
                        const float* __restrict__ fc2w, const float* __restrict__ fc2b,
                        float* __restrict__ out, int E_total, int epg)
{
    extern __shared__ char sm[];
    const int tid = threadIdx.x;
    const int g = blockIdx.x;
    const int ebase = g * epg, nbase = g * NPG;
    const int wg = tid >> 6, lane = tid & 63;
    const int l31 = lane & 31, hh = lane >> 5;
    const int ht  = wg & 1;          // f-tile: cols 32*ht..+31
    const int Mt0 = (wg >> 1) * 2;   // n'-tile pair base
    const int fo  = ht * 32 + l31;

    unsigned* Cm  = (unsigned*)sm;                    // overlays Tc0 (14848 <= 17408)
    float* dis    = (float*)(sm + OFF_MISC);          // 112 entries
    float* pool   = (float*)(sm + OFF_MISC + 448);
    float* gvn    = (float*)(sm + OFF_MISC + 704);
    float* zf     = (float*)(sm + OFF_MISC + 960);
    float* logits = (float*)(sm + OFF_MISC + 1088);
    float* lsep   = (float*)(sm + OFF_MISC + 1152);

    const float lam = lambda_max[g];
    const float two_l = 2.0f / lam;
    const float cl = two_l - 1.0f;

    // ---------------- u8 count matrix + dis ----------------
    for (int i = tid; i < (128 * CMW) / 4; i += 256)
        ((f4*)Cm)[i] = (f4){0.f, 0.f, 0.f, 0.f};
    bar_lgkm();
    for (int e = tid; e < epg; e += 256) {
        int r = ei[ebase + e] - nbase;
        int c = ei[E_total + ebase + e] - nbase;
        atomicAdd(&Cm[r * CMW + (c >> 2)], 1u << (8 * (c & 3)));
    }
    bar_lgkm();
    if (tid < 112) {
        float dv = 0.f;
        if (tid < NPG) {
            unsigned s = 0;
            #pragma unroll
            for (int w = 0; w < 25; w++) {   // cols 0..99 live in words 0..24
                unsigned u = Cm[tid * CMW + w];
                s += (u & 255) + ((u >> 8) & 255) + ((u >> 16) & 255) + (u >> 24);
            }
            dv = s > 0 ? rsqrtf((float)s) : 0.f;
        }
        dis[tid] = dv;
    }
    bar_lgkm();

    // ---------------- A-hat fragments -> registers (once) ----------------
    bf8 af[2][7];
    #pragma unroll
    for (int m = 0; m < 2; m++) {
        int rr = 32 * (Mt0 + m) + l31;
        bool rv = (rr < NPG);
        float base = rv ? (-two_l * dis[rr]) : 0.f;
        #pragma unroll
        for (int Ks = 0; Ks < 7; Ks++) {
            int k0 = Ks * 16 + 8 * hh;
            unsigned w0 = rv ? Cm[rr * CMW + (k0 >> 2)]     : 0u;
            unsigned w1 = rv ? Cm[rr * CMW + (k0 >> 2) + 1] : 0u;
            float vv[8];
            #pragma unroll
            for (int j = 0; j < 8; j++) {
                int k = k0 + j;
                unsigned cnt = (((j < 4) ? w0 : w1) >> (8 * (k & 3))) & 255u;
                float v = base * (float)cnt * dis[k];
                if (rv && k == rr) v += cl;
                vv[j] = v;
            }
            BF8U t;
            #pragma unroll
            for (int p = 0; p < 4; p++) t.u[p] = cvt_pk_bf16(vv[2 * p], vv[2 * p + 1]);
            af[m][Ks] = t.b;
        }
    }
    bar_lgkm();   // Cm reads done before Tc0 (overlay) is zeroed

    // ---------------- zero parity-0 buffers (stage 1 fully overwrites parity-1) ----------------
    for (int i = tid; i < SZ_TC / 16; i += 256)
        ((f4*)sm)[i] = (f4){0.f, 0.f, 0.f, 0.f};
    for (int i = tid; i < SZ_TRM / 16; i += 256)
        ((f4*)(sm + OFF_TRM))[i] = (f4){0.f, 0.f, 0.f, 0.f};
    if (tid < HF) pool[tid] = 0.f;
    bar_lgkm();
    if (tid < NPG) {
        unsigned short h0 = f2bf(x[(nbase + tid) * 3 + 0]);
        unsigned short h1 = f2bf(x[(nbase + tid) * 3 + 1]);
        unsigned short h2 = f2bf(x[(nbase + tid) * 3 + 2]);
        *(unsigned*)(sm + OFF_TRM + (tid * ST) * 2) = (unsigned)h0 | ((unsigned)h1 << 16);
        *(unsigned short*)(sm + OFF_TRM + (tid * ST + 2) * 2) = h2;
        *(unsigned short*)(sm + (0 * SAT + tid) * 2) = h0;
        *(unsigned short*)(sm + (1 * SAT + tid) * 2) = h1;
        *(unsigned short*)(sm + (2 * SAT + tid) * 2) = h2;
    }
    bar_lgkm();

    // ---------------- 3 ChebConv layers ----------------
    f16v acc[2];
    unsigned prev[2][8], oldr[2][8];   // packed-bf16 T_{s-1}, T_{s-2} at (np, fo) lane positions
    const float* bsv[3] = {b1, b2, b3};

    for (int L = 0; L < 3; L++) {
        const bool l1 = (L == 0);
        const unsigned short* Wl = l1 ? Wt : (Wt + (L == 1 ? 5120 : 25600));
        const int pb = L & 1;                      // parity of T0 for this layer
        const float bias = bsv[L][fo];             // hoisted: global load hidden under stages
        acc[0] = zerov16();
        acc[1] = zerov16();

        // prev = T0 at C-layout positions. For L>=1 it is already in registers.
        if (L == 0) {
            #pragma unroll
            for (int m = 0; m < 2; m++) {
                unsigned short tv[16];
                #pragma unroll
                for (int r = 0; r < 16; r++) {
                    int np = (Mt0 + m) * 32 + (r & 3) + 8 * (r >> 2) + 4 * hh;
                    tv[r] = *(const unsigned short*)(sm + OFF_TRM + (np * ST + fo) * 2);
                }
                #pragma unroll
                for (int p = 0; p < 8; p++)
                    prev[m][p] = (unsigned)tv[2 * p] | ((unsigned)tv[2 * p + 1] << 16);
            }
        }

        auto TW = [&](int k5, const char* trb) {
            const int nKs = l1 ? 1 : 4;
            for (int Ks = 0; Ks < nKs; Ks++) {
                bf8 bw;
                if (l1) bw = *(const bf8*)(Wl + (k5 * 64 + fo) * 16 + 8 * hh);
                else    bw = *(const bf8*)(Wl + (k5 * 64 + fo) * 64 + Ks * 16 + 8 * hh);
                #pragma unroll
                for (int m = 0; m < 2; m++) {
                    bf8 a = *(const bf8*)(trb +
                              (((Mt0 + m) * 32 + l31) * ST + Ks * 16 + 8 * hh) * 2);
                    acc[m] = __builtin_amdgcn_mfma_f32_32x32x16_bf16(a, bw, acc[m], 0, 0, 0);
                }
            }
        };

        for (int s = 1; s <= 4; s++) {
            const int rp = (pb + s - 1) & 1, wp = rp ^ 1;
            const char* tcR = sm + rp * SZ_TC;
            const char* trR = sm + OFF_TRM + rp * SZ_TRM;
            char* tcW = sm + wp * SZ_TC;
            char* trW = sm + OFF_TRM + wp * SZ_TRM;

            // TW(s-1): consumes prev (= T_{s-1}) and Trm[rp]; weight loads issue
            // first post-barrier and overlap the bfr ds_reads below.
            TW(s - 1, trR);

            // B-frags: Tc[rp] rows (this lane's fo column set), b128, conflict-free
            bf8 bfr[7];
            #pragma unroll
            for (int Ks = 0; Ks < 7; Ks++)
                bfr[Ks] = *(const bf8*)(tcR + (fo * SAT + Ks * 16 + 8 * hh) * 2);

            #pragma unroll
            for (int m = 0; m < 2; m++) {
                f16v c = zerov16();
                #pragma unroll
                for (int Ks = 0; Ks < 7; Ks++)
                    c = __builtin_amdgcn_mfma_f32_32x32x16_bf16(af[m][Ks], bfr[Ks], c, 0, 0, 0);
                // Chebyshev recurrence + pack
                #pragma unroll
                for (int p = 0; p < 8; p++) {
                    float ve = c[2 * p], vo = c[2 * p + 1];
                    if (s >= 2) {
                        unsigned o = oldr[m][p];
                        ve = 2.f * ve - __uint_as_float(o << 16);
                        vo = 2.f * vo - __uint_as_float(o & 0xffff0000u);
                    }
                    oldr[m][p] = prev[m][p];
                    prev[m][p] = cvt_pk_bf16(ve, vo);
                }
                // Tc[wp] writes (node-quads contiguous -> 4x b64); dead at s==4
                if (s < 4) {
                    #pragma unroll
                    for (int q4 = 0; q4 < 4; q4++) {
                        int np0 = (Mt0 + m) * 32 + 8 * q4 + 4 * hh;
                        uint2 pk;
                        pk.x = prev[m][2 * q4];
                        pk.y = prev[m][2 * q4 + 1];
                        *(uint2*)(tcW + (fo * SAT + np0) * 2) = pk;
                    }
                }
                // Trm[wp] writes: b16 lo + b16 hi per packed pair (rows npb, npb+1)
                #pragma unroll
                for (int p = 0; p < 8; p++) {
                    int r0 = 2 * p;
                    int npb = (Mt0 + m) * 32 + (r0 & 3) + 8 * (r0 >> 2) + 4 * hh;
                    char* ad = trW + (npb * ST + fo) * 2;
                    *(unsigned short*)ad = (unsigned short)prev[m][p];
                    *(unsigned short*)(ad + ST * 2) = (unsigned short)(prev[m][p] >> 16);
                }
            }
            bar_lgkm();   // single barrier: T_s visible; also covers next stage's WAR
        }

        // TW(4): T_4 is at parity (pb+4)&1 = pb
        TW(4, sm + OFF_TRM + pb * SZ_TRM);

        if (L < 2) {
            // ReLU + bias -> prev (= next layer's T0) and parity pb^1 buffers
            // (next layer reads pb^1; stage-4 already stopped reading pb^1 before
            //  its barrier, and TW(4) reads parity pb -> no extra barrier needed)
            const int op = pb ^ 1;
            char* tcW = sm + op * SZ_TC;
            char* trW = sm + OFF_TRM + op * SZ_TRM;
            #pragma unroll
            for (int m = 0; m < 2; m++) {
                #pragma unroll
                for (int p = 0; p < 8; p++) {
                    float ve = fmaxf(acc[m][2 * p]     + bias, 0.f);
                    float vo = fmaxf(acc[m][2 * p + 1] + bias, 0.f);
                    prev[m][p] = cvt_pk_bf16(ve, vo);
                }
                #pragma unroll
                for (int q4 = 0; q4 < 4; q4++) {
                    int np0 = (Mt0 + m) * 32 + 8 * q4 + 4 * hh;
                    uint2 pk;
                    pk.x = prev[m][2 * q4];
                    pk.y = prev[m][2 * q4 + 1];
                    *(uint2*)(tcW + (fo * SAT + np0) * 2) = pk;
                }
                #pragma unroll
                for (int p = 0; p < 8; p++) {
                    int r0 = 2 * p;
                    int npb = (Mt0 + m) * 32 + (r0 & 3) + 8 * (r0 >> 2) + 4 * hh;
                    char* ad = trW + (npb * ST + fo) * 2;
                    *(unsigned short*)ad = (unsigned short)prev[m][p];
                    *(unsigned short*)(ad + ST * 2) = (unsigned short)(prev[m][p] >> 16);
                }
            }
            bar_lgkm();
        } else {
            float ssum = 0.f;
            #pragma unroll
            for (int m = 0; m < 2; m++) {
                #pragma unroll
                for (int r = 0; r < 16; r++) {
                    int np = (Mt0 + m) * 32 + (r & 3) + 8 * (r >> 2) + 4 * hh;
                    float h = fmaxf(acc[m][r] + bias, 0.f);
                    if (np < NPG) ssum += h;
                }
            }
            ssum += __shfl_xor(ssum, 32, 64);
            if (hh == 0) atomicAdd(&pool[fo], ssum);
            bar_lgkm();
        }
    }

    // ---------------- BN + MLP + log_softmax ----------------
    if (tid < HF) {
        float gv = pool[tid] * (1.0f / NPG);
        gv = (gv - bnm[tid]) * rsqrtf(bnv[tid] + 1e-5f) * bng[tid] + bnb[tid];
        gvn[tid] = gv;
    }
    bar_lgkm();
    if (tid < 32) {
        float a = fc1b[tid];
        for (int f = 0; f < HF; f++) a += gvn[f] * fc1w[f * 32 + tid];
        zf[tid] = fmaxf(a, 0.f);
    }
    bar_lgkm();
    if (tid < 10) {
        float a = fc2b[tid];
        for (int k = 0; k < 32; k++) a += zf[k] * fc2w[k * 10 + tid];
        logits[tid] = a;
    }
    bar_lgkm();
    if (tid == 0) {
        float m = logits[0];
        for (int i = 1; i < 10; i++) m = fmaxf(m, logits[i]);
        float s = 0.f;
        for (int i = 0; i < 10; i++) s += expf(logits[i] - m);
        lsep[0] = m + logf(s);
    }
    bar_lgkm();
    if (tid < 10) out[g * 10 + tid] = logits[tid] - lsep[0];
}

extern "C" void kernel_launch(void* const* d_in, const int* in_sizes, int n_in,
                              void* d_out, int out_size, void* d_ws, size_t ws_size,
                              hipStream_t stream) {
    const float* x    = (const float*)d_in[0];
    const int*   ei   = (const int*)d_in[1];
    const float* lmax = (const float*)d_in[3];
    const float* W1   = (const float*)d_in[4];
    const float* b1   = (const float*)d_in[5];
    const float* W2   = (const float*)d_in[6];
    const float* b2   = (const float*)d_in[7];
    const float* W3   = (const float*)d_in[8];
    const float* b3   = (const float*)d_in[9];
    const float* bng  = (const float*)d_in[10];
    const float* bnb  = (const float*)d_in[11];
    const float* bnm  = (const float*)d_in[12];
    const float* bnv  = (const float*)d_in[13];
    const float* fc1w = (const float*)d_in[14];
    const float* fc1b = (const float*)d_in[15];
    const float* fc2w = (const float*)d_in[16];
    const float* fc2b = (const float*)d_in[17];

    const int E = in_sizes[1] / 2;
    const int G = in_sizes[3];
    const int epg = E / G;

    unsigned short* Wt = (unsigned short*)d_ws;

    wconv<<<(WT_TOTAL + 255) / 256, 256, 0, stream>>>(W1, W2, W3, Wt);

    hipFuncSetAttribute((const void*)chebreg,
                        hipFuncAttributeMaxDynamicSharedMemorySize, SMEM_BYTES);

    chebreg<<<G, 256, SMEM_BYTES, stream>>>(x, ei, lmax, Wt, b1, b2, b3,
                                            bng, bnb, bnm, bnv, fc1w, fc1b, fc2w, fc2b,
                                            (float*)d_out, E, epg);
}